// Round 14
// baseline (1924.261 us; speedup 1.0000x reference)
//
#include <hip/hip_runtime.h>
#include <stdint.h>

#pragma clang fp contract(off)

#define HALF_ 16777216u   // (65536*512)/2

typedef float v2f __attribute__((ext_vector_type(2)));

// ---- ws layout ----
#define WS_TSLOT 386
#define WS_RCNT  388
#define WS_P1E5  392
#define TBL_OFF_B 4096
#define TBL_K0 95904
#define TBL_N  8193
#define RWL_OFF_B   81920     // 16384 x 8B
#define RWLCAP 16384u
#define PCNT_OFF_B  212992    // 65536 x 4B
#define KCNT_OFF_B  475136    // 65536 x 4B
#define BG_OFF_B    786432    // interleaved (b,g): 64x512xfloat4 = 512KB
#define DYN2_OFF_B  1310720
#define PCAP_BLK 128u
#define KCAP_BLK 128u
#define NBLK 65536u
#define P1WL_OFF_B  DYN2_OFF_B
#define KWL_OFF_B   (DYN2_OFF_B + 33554432u)
#define NEED_V5     (KWL_OFF_B + 33554432u)
// v2 fallback layout (r11-verified)
#define V2WL_OFF_B 40960
#define V2WLCAP 16384u
#define V2BT_OFF_B 172032

// ---------------- threefry2x32, JAX-exact ----------------
__device__ __forceinline__ void tf2x32(uint32_t k0, uint32_t k1,
                                       uint32_t x0, uint32_t x1,
                                       uint32_t& o0, uint32_t& o1) {
  uint32_t ks2 = k0 ^ k1 ^ 0x1BD11BDAu;
  x0 += k0; x1 += k1;
#define TFR(r) x0 += x1; x1 = (x1 << (r)) | (x1 >> (32 - (r))); x1 ^= x0;
  TFR(13) TFR(15) TFR(26) TFR(6)
  x0 += k1;  x1 += ks2 + 1u;
  TFR(17) TFR(29) TFR(16) TFR(24)
  x0 += ks2; x1 += k0 + 2u;
  TFR(13) TFR(15) TFR(26) TFR(6)
  x0 += k0;  x1 += k1 + 3u;
  TFR(17) TFR(29) TFR(16) TFR(24)
  x0 += k1;  x1 += ks2 + 4u;
  TFR(13) TFR(15) TFR(26) TFR(6)
  x0 += ks2; x1 += k0 + 5u;
#undef TFR
  o0 = x0; o1 = x1;
}

__device__ __forceinline__ uint32_t tfx(uint32_t k0, uint32_t k1, uint32_t i) {
  uint32_t o0, o1;
  tf2x32(k0, k1, 0u, i, o0, o1);
  return o0 ^ o1;
}

__device__ __forceinline__ float u01(uint32_t bits) {
  return __uint_as_float((bits >> 9) | 0x3f800000u) - 1.0f;
}

__device__ __forceinline__ float csqrt(float x) {
  return (float)__builtin_sqrt((double)x);
}

// -------- XLA CPU exp (classic Cephes + backend FMA) --------
__device__ __forceinline__ float eexp(float xin) {
  float c = fminf(xin, 88.3762626647950f);
  c = fmaxf(c, -88.3762626647949f);
  float fx = floorf(__builtin_fmaf(c, 1.44269504088896341f, 0.5f));
  float x = __builtin_fmaf(-0.693359375f, fx, c);
  x = __builtin_fmaf(2.12194440e-4f, fx, x);
  float z = x * x;
  float y = __builtin_fmaf(x, 1.9875691500e-4f, 1.3981999507e-3f);
  y = __builtin_fmaf(y, x, 8.3334519073e-3f);
  y = __builtin_fmaf(y, x, 4.1665795894e-2f);
  y = __builtin_fmaf(y, x, 1.6666665459e-1f);
  y = __builtin_fmaf(y, x, 5.0000001201e-1f);
  y = __builtin_fmaf(y, z, x);
  y = 1.0f + y;
  int e = (int)fx;
  float s = __uint_as_float((uint32_t)(e + 127) << 23);
  return fmaxf(y * s, xin);
}

// -------- XLA CPU log (classic single-Horner Cephes, fused) --------
__device__ __forceinline__ float elog(float xin) {
  float x = fmaxf(xin, 1.17549435e-38f);
  uint32_t bits = __float_as_uint(x);
  float e = (float)((int)(bits >> 23) - 0x7e);
  x = __uint_as_float((bits & 0x807fffffu) | 0x3f000000u);
  bool mask = x < 0.707106781186547524f;
  float tmp = mask ? x : 0.0f;
  x = x - 1.0f;
  e = e - (mask ? 1.0f : 0.0f);
  x = x + tmp;
  float z = x * x;
  float y = __builtin_fmaf(7.0376836292e-2f, x, -1.1514610310e-1f);
  y = __builtin_fmaf(y, x, 1.1676998740e-1f);
  y = __builtin_fmaf(y, x, -1.2420140846e-1f);
  y = __builtin_fmaf(y, x, 1.4249322787e-1f);
  y = __builtin_fmaf(y, x, -1.6668057665e-1f);
  y = __builtin_fmaf(y, x, 2.0000714765e-1f);
  y = __builtin_fmaf(y, x, -2.4999993993e-1f);
  y = __builtin_fmaf(y, x, 3.3333331174e-1f);
  y = y * x;
  y = y * z;
  y = __builtin_fmaf(e, -2.12194440e-4f, y);
  y = __builtin_fmaf(-0.5f, z, y);
  x = x + y;
  x = __builtin_fmaf(e, 0.693359375f, x);
  if (xin == 0.0f) x = -__builtin_inff();
  return x;
}

__device__ __forceinline__ float xlog1p(float x) {
  float small_ = __builtin_fmaf(-0.5f, x, 1.0f) * x;
  float large_ = elog(x + 1.0f);
  return (fabsf(x) < 1e-4f) ? small_ : large_;
}

__device__ __forceinline__ float xlgamma(float input) {
  float z = input - 1.0f;
  float x = 0.99999999999980993227684700473478f;
  const float lcs[8] = {
      676.520368121885098567009190444019f,
      -1259.13921672240287047156078755283f,
      771.3234287776530788486528258894f,
      -176.61502916214059906584551354f,
      12.507343278686904814458936853f,
      -0.13857109526572011689554707f,
      9.984369578019570859563e-6f,
      1.50563273514931155834e-7f};
#pragma unroll
  for (int i = 0; i < 8; ++i) {
    x = x + lcs[i] / ((z + (float)i) + 1.0f);
  }
  float t = 7.5f + z;
  float log_t = 2.0149030205422647f + xlog1p(z / 7.5f);
  float log_y = __builtin_fmaf((z + 0.5f) - t / log_t, log_t,
                               0.91893853320467274178f) + elog(x);
  return log_y;
}

struct TrsP { float ll, bb, aa, ia, vr; };
__device__ __forceinline__ TrsP trs_params(float lam) {
  TrsP p;
  p.ll = elog(lam);
  p.bb = __builtin_fmaf(2.53f, csqrt(lam), 0.931f);
  p.aa = __builtin_fmaf(0.02483f, p.bb, -0.059f);
  p.ia = 1.1239f + 1.1328f / (p.bb - 3.4f);
  p.vr = 0.9277f - 3.6224f / (p.bb - 2.0f);
  return p;
}

__device__ __forceinline__ bool trs_step(float lam, const TrsP& p,
                                         float u, float v, float& kout) {
  float us = 0.5f - fabsf(u);
  float t2 = (2.0f * p.aa) / us + p.bb;
  float k = floorf(__builtin_fmaf(t2, u, lam) + 0.43f);
  kout = k;
  bool accept1 = (us >= 0.07f) && (v <= p.vr);
  if (accept1) return true;
  bool reject = (k < 0.0f) || ((us < 0.013f) && (v > us));
  if (reject) return false;
  float s = elog(v * p.ia / (p.aa / (us * us) + p.bb));
  float tt = __builtin_fmaf(k, p.ll, -lam) - xlgamma(k + 1.0f);
  return s <= tt;
}

// ---------------- chain + consts ----------------
__global__ void chain_v2(uint32_t* __restrict__ ws) {
  int lane = threadIdx.x;
  uint32_t kpa = 0, kpb = 0;
  if (lane == 0) {
    uint32_t a0, b0;
    tf2x32(0u, 42u, 0u, 0u, kpa, kpb);
    tf2x32(0u, 42u, 0u, 1u, a0, b0);
    ws[0] = a0; ws[1] = b0;
  }
  kpa = __shfl(kpa, 0); kpb = __shfl(kpb, 0);
  uint32_t kra = kpa, krb = kpb;
  uint32_t kja = kpa, kjb = kpb;
  for (int i = 0; i < 64; ++i) {
    bool isrej = (lane >= 2 && lane <= 4);
    uint32_t key0 = isrej ? kja : kra;
    uint32_t key1 = isrej ? kjb : krb;
    uint32_t xx = (lane == 1) ? 1u : (lane == 3) ? 1u : (lane == 4) ? 2u : 0u;
    uint32_t o0, o1;
    tf2x32(key0, key1, 0u, xx, o0, o1);
    if (lane == 1) { ws[2 + 2 * i] = o0; ws[3 + 2 * i] = o1; }
    if (lane == 3) { ws[130 + 4 * i] = o0; ws[131 + 4 * i] = o1; }
    if (lane == 4) { ws[132 + 4 * i] = o0; ws[133 + 4 * i] = o1; }
    kra = __shfl(o0, 0); krb = __shfl(o1, 0);
    kja = __shfl(o0, 2); kjb = __shfl(o1, 2);
  }
  if (lane == 0) {
    TrsP p = trs_params(1e5f);
    float* wf = (float*)(ws + WS_P1E5);
    wf[0] = p.ll; wf[1] = p.bb; wf[2] = p.aa; wf[3] = p.ia; wf[4] = p.vr;
    ws[WS_TSLOT] = 0u;
    ws[WS_RCNT] = 0u;
  }
}

__global__ __launch_bounds__(256) void lgt_kernel(uint32_t* __restrict__ ws) {
  int j = blockIdx.x * 256 + threadIdx.x;
  if (j >= TBL_N) return;
  float* tbl = (float*)((char*)ws + TBL_OFF_B);
  tbl[j] = xlgamma((float)(TBL_K0 + j) + 1.0f);
}

// v2 fallback transpose
__global__ __launch_bounds__(256) void transpose_kernel(
    const float* __restrict__ b, const float* __restrict__ g,
    float* __restrict__ bT, float* __restrict__ gT) {
  int i = blockIdx.x * 256 + threadIdx.x;
  int q = i >> 7, d = i & 127;
  bT[d * 512 + q] = b[i];
  gT[d * 512 + q] = g[i];
}

// v5 interleaved transpose: bg[(d>>1)*512+q] = float4(b_2i, g_2i, b_2i+1, g_2i+1)
__global__ __launch_bounds__(256) void transpose_bg(
    const float* __restrict__ b, const float* __restrict__ g,
    float* __restrict__ bg) {
  int i = blockIdx.x * 256 + threadIdx.x;
  int q = i >> 7, d = i & 127;
  int base = ((d >> 1) * 512 + q) * 4 + (d & 1) * 2;
  bg[base] = b[i];
  bg[base + 1] = g[i];
}

// ---------------- pass1 eval (const lam = 1e5) ----------------
struct P1C { float ll, bb, aa, ia, vr; };

__device__ __forceinline__ bool p1_eval(const P1C& c, const float* __restrict__ tbl,
                                        uint32_t s00, uint32_t s01,
                                        uint32_t s10, uint32_t s11, uint32_t idx) {
  float u = u01(tfx(s00, s01, idx)) - 0.5f;
  float v = u01(tfx(s10, s11, idx));
  float us = 0.5f - fabsf(u);
  if (us >= 0.07f && v <= c.vr) return true;
  float t2 = (2.0f * c.aa) / us + c.bb;
  float k = floorf(__builtin_fmaf(t2, u, 1e5f) + 0.43f);
  if ((k < 0.0f) || ((us < 0.013f) && (v > us))) return false;
  float arg = v * c.ia / (c.aa / (us * us) + c.bb);
  int ki = (int)k - TBL_K0;
  float lg = (ki >= 0 && ki < TBL_N) ? tbl[ki] : xlgamma(k + 1.0f);
  float tt = __builtin_fmaf(k, c.ll, -1e5f) - lg;
  float sf = __logf(arg);
  if (sf <= tt - 1e-4f) return true;
  if (sf > tt + 1e-4f) return false;
  return elog(arg) <= tt;
}

__device__ uint32_t p1_scan(const P1C& c, const float* __restrict__ tbl,
                            const uint32_t* __restrict__ rej, uint32_t idx) {
  for (int it = 1; it < 64; ++it) {
    if (p1_eval(c, tbl, rej[4 * it], rej[4 * it + 1], rej[4 * it + 2],
                rej[4 * it + 3], idx))
      return (uint32_t)it;
  }
  return 63u;
}

// p1b: grid-stride over survivor slots; max-reduce into Tslot
__global__ __launch_bounds__(256) void p1b_v4(
    uint32_t* ws, const uint32_t* __restrict__ p1wl,
    const uint32_t* __restrict__ pcnt) {
  const float* wf = (const float*)(ws + WS_P1E5);
  P1C c{wf[0], wf[1], wf[2], wf[3], wf[4]};
  const float* tbl = (const float*)((const char*)ws + TBL_OFF_B);
  const uint32_t* rej = ws + 130;
  uint32_t fmax = 0;
  uint32_t total = NBLK * PCAP_BLK;
  for (uint32_t s = blockIdx.x * 256u + threadIdx.x; s < total;
       s += gridDim.x * 256u) {
    uint32_t b = s >> 7, i = s & (PCAP_BLK - 1u);
    uint32_t cnt = pcnt[b];
    if (cnt > PCAP_BLK) cnt = PCAP_BLK;
    if (i < cnt) {
      uint32_t f = p1_scan(c, tbl, rej, p1wl[s]);
      if (f > fmax) fmax = f;
    }
  }
  for (int off = 32; off > 0; off >>= 1) {
    uint32_t o = __shfl_down(fmax, off, 64);
    if (o > fmax) fmax = o;
  }
  if ((threadIdx.x & 63) == 0 && fmax > 0) atomicMax(ws + WS_TSLOT, fmax);
}

// exact first-accept with true lam (rejection elements only)
__device__ __forceinline__ int first_accept_exact(float lam, uint32_t idx,
                                                  const uint32_t* __restrict__ rej) {
  TrsP p = trs_params(lam);
  for (int it = 0; it < 64; ++it) {
    float u = u01(tfx(rej[4 * it + 0], rej[4 * it + 1], idx)) - 0.5f;
    float v = u01(tfx(rej[4 * it + 2], rej[4 * it + 3], idx));
    float kk;
    if (trs_step(lam, p, u, v, kk)) return it;
  }
  return 63;
}

// knuth finisher from state after 4 draws (k == 4), iters 4..63
__device__ float knuth_finish(float lp, float lam, bool fD, bool m,
                              const uint32_t* __restrict__ wsk, uint32_t idx) {
  const float del = 4e-6f * (lam + 4.0f);
  int k = 4;
  bool fU = false;
  for (int it = 4; it < 64; ++it) {
    float d = lp + lam;
    bool nb = fabsf(d) < del;
    if (d > 0.0f) {
      fD = nb; k++;
      lp = lp + __logf(u01(tfx(wsk[2 * it], wsk[2 * it + 1], idx)));
    } else { fU = nb; break; }
  }
  float p = (float)(k - 1);
  float ph = p + ((fD && fU) ? 0.0f : (fD ? -0.5f : (fU ? 0.5f : 0.0f)));
  return m ? ph : 0.0f;
}

// ---------------- zip v5: packed dot + fused p1 iter-0 ----------------
__global__ __launch_bounds__(256) void zip_v5(
    const float* __restrict__ z, uint32_t* ws,
    uint32_t* __restrict__ kwl, uint32_t* __restrict__ kcnt,
    uint32_t* __restrict__ p1wl, uint32_t* __restrict__ pcnt,
    float* __restrict__ out) {
  __shared__ uint32_t ldsk, ldsp;
  if (threadIdx.x == 0) { ldsk = 0; ldsp = 0; }
  __syncthreads();
  uint32_t t = blockIdx.x * 256u + threadIdx.x;
  uint32_t n = t >> 9, q = t & 511u, n2 = n + 32768u;

  const float4* z4a = (const float4*)(z + (size_t)n * 128u);
  const float4* z4b = (const float4*)(z + (size_t)n2 * 128u);
  const float4* bg4 = (const float4*)((const char*)ws + BG_OFF_B);

  // UNFUSED sequential dot chains, ascending d, packed (l,g) pairs.
  // Each component's chain is the same scalar IEEE sequence (bit-exact).
  v2f accA = {0.f, 0.f}, accB = {0.f, 0.f};
  for (int d4 = 0; d4 < 32; ++d4) {
    float4 z1 = z4a[d4], z2 = z4b[d4];
    float4 p01 = bg4[(d4 * 2 + 0) * 512 + q];
    float4 p23 = bg4[(d4 * 2 + 1) * 512 + q];
    v2f bg0 = {p01.x, p01.y}, bg1 = {p01.z, p01.w};
    v2f bg2v = {p23.x, p23.y}, bg3 = {p23.z, p23.w};
    accA = accA + bg0 * (v2f){z1.x, z1.x};
    accB = accB + bg0 * (v2f){z2.x, z2.x};
    accA = accA + bg1 * (v2f){z1.y, z1.y};
    accB = accB + bg1 * (v2f){z2.y, z2.y};
    accA = accA + bg2v * (v2f){z1.z, z1.z};
    accB = accB + bg2v * (v2f){z2.z, z2.z};
    accA = accA + bg3 * (v2f){z1.w, z1.w};
    accB = accB + bg3 * (v2f){z2.w, z2.w};
  }
  float lA = accA.x, gA = accA.y, lB = accB.x, gB = accB.y;

  float piA = 1.0f / (1.0f + eexp(-lA));
  float piB = 1.0f / (1.0f + eexp(-lB));
  float lamA = fabsf(eexp(gA)) + 0.01f;
  float lamB = fabsf(eexp(gB)) + 0.01f;

  float dmA = u01(tfx(ws[0], ws[1], t)) - (1.0f - piA);
  float dmB = u01(tfx(ws[0], ws[1], t + HALF_)) - (1.0f - piB);
  bool mA = dmA < 0.0f, mB = dmB < 0.0f;
  bool mfA = fabsf(dmA) < 2e-6f, mfB = fabsf(dmB) < 2e-6f;

  bool knuA = lamA < 10.0f, knuB = lamB < 10.0f;

  // knuth chunk: exactly iterations 0..3
  const uint32_t* wsk = ws + 2;
  const float delA = 4e-6f * (lamA + 4.0f);
  const float delB = 4e-6f * (lamB + 4.0f);
  float lpA = 0.f, lpB = 0.f;
  int kA = 0, kB = 0;
  bool goA = knuA, goB = knuB;
  bool fDA = false, fUA = false, fDB = false, fUB = false;
#pragma unroll
  for (int it = 0; it < 4; ++it) {
    uint32_t w0 = wsk[2 * it], w1 = wsk[2 * it + 1];
    if (goA) {
      float d = lpA + lamA;
      bool nb = fabsf(d) < delA;
      if (d > 0.0f) { fDA = nb; kA++; lpA = lpA + __logf(u01(tfx(w0, w1, t))); }
      else          { fUA = nb; goA = false; }
    }
    if (goB) {
      float d = lpB + lamB;
      bool nb = fabsf(d) < delB;
      if (d > 0.0f) { fDB = nb; kB++; lpB = lpB + __logf(u01(tfx(w0, w1, t + HALF_))); }
      else          { fUB = nb; goB = false; }
    }
  }
  bool survA = knuA && goA, survB = knuB && goB;

  // fused p1 iter-0 (const lam=1e5) for KNUTH elements; survivors -> p1 region
  {
    const float* wf = (const float*)(ws + WS_P1E5);
    P1C c{wf[0], wf[1], wf[2], wf[3], wf[4]};
    const float* tbl = (const float*)((const char*)ws + TBL_OFF_B);
    const uint32_t* rej = ws + 130;
    uint32_t s00 = rej[0], s01 = rej[1], s10 = rej[2], s11 = rej[3];
    uint32_t* pregion = p1wl + blockIdx.x * PCAP_BLK;
    if (knuA && !p1_eval(c, tbl, s00, s01, s10, s11, t)) {
      uint32_t slot = atomicAdd(&ldsp, 1u);
      if (slot < PCAP_BLK) pregion[slot] = t;
      else atomicMax(ws + WS_TSLOT, p1_scan(c, tbl, rej, t));
    }
    if (knuB && !p1_eval(c, tbl, s00, s01, s10, s11, t + HALF_)) {
      uint32_t slot = atomicAdd(&ldsp, 1u);
      if (slot < PCAP_BLK) pregion[slot] = t + HALF_;
      else atomicMax(ws + WS_TSLOT, p1_scan(c, tbl, rej, t + HALF_));
    }
  }

  // rejection elements: exact first-accept -> T; push to rej WL (rare)
  const uint32_t* rejk = ws + 130;
  uint32_t* rwl = (uint32_t*)((char*)ws + RWL_OFF_B);
  if (!knuA) {
    atomicMax(ws + WS_TSLOT, (uint32_t)first_accept_exact(lamA, t, rejk));
    uint32_t slot = atomicAdd(ws + WS_RCNT, 1u);
    if (slot < RWLCAP) {
      rwl[2 * slot] = t | (mA ? 0x80000000u : 0u);
      rwl[2 * slot + 1] = __float_as_uint(lamA);
    }
  }
  if (!knuB) {
    atomicMax(ws + WS_TSLOT, (uint32_t)first_accept_exact(lamB, t + HALF_, rejk));
    uint32_t slot = atomicAdd(ws + WS_RCNT, 1u);
    if (slot < RWLCAP) {
      rwl[2 * slot] = (t + HALF_) | (mB ? 0x80000000u : 0u);
      rwl[2 * slot + 1] = __float_as_uint(lamB);
    }
  }

  // knuth survivors -> per-block region (LDS counter); k3b recomputes lam/lp
  uint32_t* region = kwl + blockIdx.x * KCAP_BLK;
  if (survA) {
    uint32_t slot = atomicAdd(&ldsk, 1u);
    if (slot < KCAP_BLK) region[slot] = t | ((uint32_t)mA << 25);
    else out[t] = knuth_finish(lpA, lamA, fDA, mA, wsk, t);
  } else if (knuA) {
    float pA = (float)(kA - 1);
    float hiA = pA + (fUA ? 0.5f : 0.0f);
    float resA;
    if (mfA && hiA <= 1.2f) resA = 0.5f * hiA;
    else {
      float ph = pA + ((fDA && fUA) ? 0.0f : (fDA ? -0.5f : (fUA ? 0.5f : 0.0f)));
      resA = mA ? ph : 0.0f;
    }
    out[t] = resA;
  } else {
    out[t] = 0.0f;  // k3 overwrites
  }

  if (survB) {
    uint32_t slot = atomicAdd(&ldsk, 1u);
    if (slot < KCAP_BLK) region[slot] = (t + HALF_) | ((uint32_t)mB << 25);
    else out[t + HALF_] = knuth_finish(lpB, lamB, fDB, mB, wsk, t + HALF_);
  } else if (knuB) {
    float pB = (float)(kB - 1);
    float hiB = pB + (fUB ? 0.5f : 0.0f);
    float resB;
    if (mfB && hiB <= 1.2f) resB = 0.5f * hiB;
    else {
      float ph = pB + ((fDB && fUB) ? 0.0f : (fDB ? -0.5f : (fUB ? 0.5f : 0.0f)));
      resB = mB ? ph : 0.0f;
    }
    out[t + HALF_] = resB;
  } else {
    out[t + HALF_] = 0.0f;
  }
  __syncthreads();
  if (threadIdx.x == 0) { kcnt[blockIdx.x] = ldsk; pcnt[blockIdx.x] = ldsp; }
}

// k3b v5: finish knuth survivors; recompute lam (bit-exact gamma chain) and lp
__global__ __launch_bounds__(256) void k3b_v5(
    uint32_t* ws, const float* __restrict__ z,
    const uint32_t* __restrict__ kwl, const uint32_t* __restrict__ kcnt,
    float* __restrict__ out) {
  const uint32_t* wsk = ws + 2;
  const float4* bg4 = (const float4*)((const char*)ws + BG_OFF_B);
  uint32_t total = NBLK * KCAP_BLK;
  for (uint32_t s = blockIdx.x * 256u + threadIdx.x; s < total;
       s += gridDim.x * 256u) {
    uint32_t b = s >> 7, i = s & (KCAP_BLK - 1u);
    uint32_t cnt = kcnt[b];
    if (cnt > KCAP_BLK) cnt = KCAP_BLK;
    if (i >= cnt) continue;
    uint32_t w = kwl[s];
    uint32_t idx = w & 0x01FFFFFFu;
    bool m = (w >> 25) & 1u;
    uint32_t n = idx >> 9, q = idx & 511u;
    const float4* z4 = (const float4*)(z + (size_t)n * 128u);
    // UNFUSED gamma chain, same ascending order & rounding as zip's accA.y
    float g = 0.f;
    for (int d4 = 0; d4 < 32; ++d4) {
      float4 z1 = z4[d4];
      float4 p01 = bg4[(d4 * 2 + 0) * 512 + q];
      float4 p23 = bg4[(d4 * 2 + 1) * 512 + q];
      g = g + p01.y * z1.x;
      g = g + p01.w * z1.y;
      g = g + p23.y * z1.z;
      g = g + p23.w * z1.w;
    }
    float lam = fabsf(eexp(g)) + 0.01f;
    // replay iterations 0..3 (d>0 guaranteed for survivors)
    const float del = 4e-6f * (lam + 4.0f);
    float lp = 0.f;
    bool fD = false;
#pragma unroll
    for (int it = 0; it < 4; ++it) {
      float d = lp + lam;
      fD = fabsf(d) < del;
      lp = lp + __logf(u01(tfx(wsk[2 * it], wsk[2 * it + 1], idx)));
    }
    out[idx] = knuth_finish(lp, lam, fD, m, wsk, idx);
  }
}

// k3: rejection last-accept with final T
__global__ __launch_bounds__(256) void k3_kernel(
    const uint32_t* ws, const uint32_t* __restrict__ wl, uint32_t cap,
    float* __restrict__ out) {
  uint32_t cnt = ws[WS_RCNT];
  if (cnt > cap) cnt = cap;
  uint32_t Traw = ws[WS_TSLOT];
  int Tmax = (int)(Traw > 63u ? 63u : Traw);
  const uint32_t* rej = ws + 130;
  for (uint32_t i = blockIdx.x * 256u + threadIdx.x; i < cnt;
       i += gridDim.x * 256u) {
    uint32_t im = wl[2 * i];
    float lam = __uint_as_float(wl[2 * i + 1]);
    uint32_t idx = im & 0x7FFFFFFFu;
    bool mask = (im >> 31) != 0u;
    TrsP p = trs_params(lam);
    float klast = -1.0f;
    for (int it = 0; it <= Tmax; ++it) {
      float u = u01(tfx(rej[4 * it + 0], rej[4 * it + 1], idx)) - 0.5f;
      float v = u01(tfx(rej[4 * it + 2], rej[4 * it + 3], idx));
      float kk;
      if (trs_step(lam, p, u, v, kk)) klast = kk;
    }
    out[idx] = mask ? klast : 0.0f;
  }
}

// ================= v2 fallback (r11-verified) =================

__global__ __launch_bounds__(256) void pass1_lite(
    const uint32_t* __restrict__ chain, uint32_t* __restrict__ Tslot) {
  const float* wf = (const float*)(chain + WS_P1E5);
  P1C c{wf[0], wf[1], wf[2], wf[3], wf[4]};
  const float* tbl = (const float*)((const char*)chain + TBL_OFF_B);
  uint32_t t = blockIdx.x * 256u + threadIdx.x;
  const uint32_t* rej = chain + 130;
  int faA = 63, faB = 63;
  bool accA = false, accB = false;
  for (int it = 0; it < 64; ++it) {
    if (accA && accB) break;
    uint32_t s00 = rej[4 * it + 0], s01 = rej[4 * it + 1];
    uint32_t s10 = rej[4 * it + 2], s11 = rej[4 * it + 3];
    if (!accA && p1_eval(c, tbl, s00, s01, s10, s11, t)) { accA = true; faA = it; }
    if (!accB && p1_eval(c, tbl, s00, s01, s10, s11, t + HALF_)) { accB = true; faB = it; }
  }
  int fa = faA > faB ? faA : faB;
  for (int off = 32; off > 0; off >>= 1) {
    int o = __shfl_down(fa, off, 64);
    fa = fa > o ? fa : o;
  }
  __shared__ int smax[4];
  int wave = threadIdx.x >> 6, lanei = threadIdx.x & 63;
  if (lanei == 0) smax[wave] = fa;
  __syncthreads();
  if (threadIdx.x == 0) {
    int m01 = smax[0] > smax[1] ? smax[0] : smax[1];
    int m23 = smax[2] > smax[3] ? smax[2] : smax[3];
    int m = m01 > m23 ? m01 : m23;
    atomicMax(Tslot, (uint32_t)m);
  }
}

__global__ __launch_bounds__(256) void zip_v2(
    const float* __restrict__ z, const float* __restrict__ bT,
    const float* __restrict__ gT, uint32_t* ws, float* __restrict__ out) {
  uint32_t t = blockIdx.x * 256u + threadIdx.x;
  uint32_t n = t >> 9, q = t & 511u, n2 = n + 32768u;
  const float* zr  = z + (size_t)n * 128u;
  const float* zr2 = z + (size_t)n2 * 128u;
  float lA = 0.f, lB = 0.f, gA = 0.f, gB = 0.f;
  for (int d = 0; d < 128; ++d) {
    float bv = bT[d * 512 + q];
    float gv = gT[d * 512 + q];
    float z1 = zr[d], z2 = zr2[d];
    lA = lA + z1 * bv;
    lB = lB + z2 * bv;
    gA = gA + z1 * gv;
    gB = gB + z2 * gv;
  }
  float piA = 1.0f / (1.0f + eexp(-lA));
  float piB = 1.0f / (1.0f + eexp(-lB));
  float lamA = fabsf(eexp(gA)) + 0.01f;
  float lamB = fabsf(eexp(gB)) + 0.01f;
  bool knuA = lamA < 10.0f, knuB = lamB < 10.0f;
  float pA = 0.f, pB = 0.f;
  bool fDA = false, fUA = false, fDB = false, fUB = false;
  {
    const uint32_t* wsk = ws + 2;
    const float delA = 4e-6f * (lamA + 4.0f);
    const float delB = 4e-6f * (lamB + 4.0f);
    float lpA = 0.f, lpB = 0.f;
    int kA = 0, kB = 0;
    bool goA = knuA, goB = knuB;
    for (int it = 0; it < 64; ++it) {
      if (!goA && !goB) break;
      uint32_t w0 = wsk[2 * it], w1 = wsk[2 * it + 1];
      if (goA) {
        float d = lpA + lamA;
        bool nb = fabsf(d) < delA;
        if (d > 0.0f) { fDA = nb; kA++; lpA = lpA + __logf(u01(tfx(w0, w1, t))); }
        else          { fUA = nb; goA = false; }
      }
      if (goB) {
        float d = lpB + lamB;
        bool nb = fabsf(d) < delB;
        if (d > 0.0f) { fDB = nb; kB++; lpB = lpB + __logf(u01(tfx(w0, w1, t + HALF_))); }
        else          { fUB = nb; goB = false; }
      }
    }
    if (knuA) pA = (float)(kA - 1);
    if (knuB) pB = (float)(kB - 1);
  }
  float dmA = u01(tfx(ws[0], ws[1], t)) - (1.0f - piA);
  float dmB = u01(tfx(ws[0], ws[1], t + HALF_)) - (1.0f - piB);
  bool mA = dmA < 0.0f, mB = dmB < 0.0f;
  bool mfA = fabsf(dmA) < 2e-6f, mfB = fabsf(dmB) < 2e-6f;
  uint32_t* wl = (uint32_t*)((char*)ws + V2WL_OFF_B);
  const uint32_t* rejk = ws + 130;
  float resA, resB;
  if (!knuA) {
    atomicMax(ws + WS_TSLOT, (uint32_t)first_accept_exact(lamA, t, rejk));
    uint32_t slot = atomicAdd(ws + WS_RCNT, 1u);
    if (slot < V2WLCAP) {
      wl[2 * slot] = t | (mA ? 0x80000000u : 0u);
      wl[2 * slot + 1] = __float_as_uint(lamA);
    }
    resA = 0.0f;
  } else {
    float hiA = pA + (fUA ? 0.5f : 0.0f);
    if (mfA && hiA <= 1.2f) resA = 0.5f * hiA;
    else {
      float ph = pA + ((fDA && fUA) ? 0.0f : (fDA ? -0.5f : (fUA ? 0.5f : 0.0f)));
      resA = mA ? ph : 0.0f;
    }
  }
  if (!knuB) {
    atomicMax(ws + WS_TSLOT, (uint32_t)first_accept_exact(lamB, t + HALF_, rejk));
    uint32_t slot = atomicAdd(ws + WS_RCNT, 1u);
    if (slot < V2WLCAP) {
      wl[2 * slot] = (t + HALF_) | (mB ? 0x80000000u : 0u);
      wl[2 * slot + 1] = __float_as_uint(lamB);
    }
    resB = 0.0f;
  } else {
    float hiB = pB + (fUB ? 0.5f : 0.0f);
    if (mfB && hiB <= 1.2f) resB = 0.5f * hiB;
    else {
      float ph = pB + ((fDB && fUB) ? 0.0f : (fDB ? -0.5f : (fUB ? 0.5f : 0.0f)));
      resB = mB ? ph : 0.0f;
    }
  }
  out[t] = resA;
  out[t + HALF_] = resB;
}

extern "C" void kernel_launch(void* const* d_in, const int* in_sizes, int n_in,
                              void* d_out, int out_size, void* d_ws, size_t ws_size,
                              hipStream_t stream) {
  const float* z     = (const float*)d_in[0];
  const float* beta  = (const float*)d_in[1];
  const float* gamma = (const float*)d_in[2];
  float* out = (float*)d_out;
  uint32_t* ws = (uint32_t*)d_ws;

  if (ws_size >= NEED_V5) {
    float* bg = (float*)((char*)d_ws + BG_OFF_B);
    uint32_t* p1wl = (uint32_t*)((char*)d_ws + P1WL_OFF_B);
    uint32_t* kwl  = (uint32_t*)((char*)d_ws + KWL_OFF_B);
    uint32_t* pcnt = (uint32_t*)((char*)d_ws + PCNT_OFF_B);
    uint32_t* kcnt = (uint32_t*)((char*)d_ws + KCNT_OFF_B);
    uint32_t* rwl  = (uint32_t*)((char*)d_ws + RWL_OFF_B);

    chain_v2<<<1, 64, 0, stream>>>(ws);
    lgt_kernel<<<(TBL_N + 255) / 256, 256, 0, stream>>>(ws);
    transpose_bg<<<256, 256, 0, stream>>>(beta, gamma, bg);
    zip_v5<<<NBLK, 256, 0, stream>>>(z, ws, kwl, kcnt, p1wl, pcnt, out);
    p1b_v4<<<2048, 256, 0, stream>>>(ws, p1wl, pcnt);
    k3b_v5<<<2048, 256, 0, stream>>>(ws, z, kwl, kcnt, out);
    k3_kernel<<<64, 256, 0, stream>>>(ws, rwl, RWLCAP, out);
  } else {
    float* bT = (float*)((char*)d_ws + V2BT_OFF_B);
    float* gT = bT + 512 * 128;
    uint32_t* rwl = (uint32_t*)((char*)d_ws + V2WL_OFF_B);
    chain_v2<<<1, 64, 0, stream>>>(ws);
    lgt_kernel<<<(TBL_N + 255) / 256, 256, 0, stream>>>(ws);
    transpose_kernel<<<256, 256, 0, stream>>>(beta, gamma, bT, gT);
    pass1_lite<<<HALF_ / 256u, 256, 0, stream>>>(ws, ws + WS_TSLOT);
    zip_v2<<<HALF_ / 256u, 256, 0, stream>>>(z, bT, gT, ws, out);
    k3_kernel<<<64, 256, 0, stream>>>(ws, rwl, V2WLCAP, out);
  }
}

// Round 15
// 1590.469 us; speedup vs baseline: 1.2099x; 1.2099x over previous
//
#include <hip/hip_runtime.h>
#include <stdint.h>

#pragma clang fp contract(off)

#define HALF_ 16777216u   // (65536*512)/2

// ---- ws layout ----
#define WS_TSLOT 386
#define WS_RCNT  388
#define WS_P1E5  392
#define TBL_OFF_B 4096
#define TBL_K0 95904
#define TBL_N  8193
#define RWL_OFF_B   81920     // 16384 x 8B
#define RWLCAP 16384u
#define PCNT_OFF_B  212992    // 65536 x 4B
#define KCNT_OFF_B  475136    // 65536 x 4B
#define BTT_OFF_B   786432    // 256KB tiled
#define GTT_OFF_B   1048576   // 256KB tiled
#define DYN2_OFF_B  1310720
#define PCAP_BLK 128u
#define KCAP_BLK 128u
#define NBLK 65536u
#define P1WL_OFF_B  DYN2_OFF_B
#define KWL_OFF_B   (DYN2_OFF_B + 33554432u)
#define NEED_V4     (KWL_OFF_B + 33554432u)
// v2 fallback layout (r11-verified)
#define V2WL_OFF_B 40960
#define V2WLCAP 16384u
#define V2BT_OFF_B 172032

// ---------------- threefry2x32, JAX-exact ----------------
__device__ __forceinline__ void tf2x32(uint32_t k0, uint32_t k1,
                                       uint32_t x0, uint32_t x1,
                                       uint32_t& o0, uint32_t& o1) {
  uint32_t ks2 = k0 ^ k1 ^ 0x1BD11BDAu;
  x0 += k0; x1 += k1;
#define TFR(r) x0 += x1; x1 = (x1 << (r)) | (x1 >> (32 - (r))); x1 ^= x0;
  TFR(13) TFR(15) TFR(26) TFR(6)
  x0 += k1;  x1 += ks2 + 1u;
  TFR(17) TFR(29) TFR(16) TFR(24)
  x0 += ks2; x1 += k0 + 2u;
  TFR(13) TFR(15) TFR(26) TFR(6)
  x0 += k0;  x1 += k1 + 3u;
  TFR(17) TFR(29) TFR(16) TFR(24)
  x0 += k1;  x1 += ks2 + 4u;
  TFR(13) TFR(15) TFR(26) TFR(6)
  x0 += ks2; x1 += k0 + 5u;
#undef TFR
  o0 = x0; o1 = x1;
}

__device__ __forceinline__ uint32_t tfx(uint32_t k0, uint32_t k1, uint32_t i) {
  uint32_t o0, o1;
  tf2x32(k0, k1, 0u, i, o0, o1);
  return o0 ^ o1;
}

__device__ __forceinline__ float u01(uint32_t bits) {
  return __uint_as_float((bits >> 9) | 0x3f800000u) - 1.0f;
}

__device__ __forceinline__ float csqrt(float x) {
  return (float)__builtin_sqrt((double)x);
}

// -------- XLA CPU exp (classic Cephes + backend FMA) --------
__device__ __forceinline__ float eexp(float xin) {
  float c = fminf(xin, 88.3762626647950f);
  c = fmaxf(c, -88.3762626647949f);
  float fx = floorf(__builtin_fmaf(c, 1.44269504088896341f, 0.5f));
  float x = __builtin_fmaf(-0.693359375f, fx, c);
  x = __builtin_fmaf(2.12194440e-4f, fx, x);
  float z = x * x;
  float y = __builtin_fmaf(x, 1.9875691500e-4f, 1.3981999507e-3f);
  y = __builtin_fmaf(y, x, 8.3334519073e-3f);
  y = __builtin_fmaf(y, x, 4.1665795894e-2f);
  y = __builtin_fmaf(y, x, 1.6666665459e-1f);
  y = __builtin_fmaf(y, x, 5.0000001201e-1f);
  y = __builtin_fmaf(y, z, x);
  y = 1.0f + y;
  int e = (int)fx;
  float s = __uint_as_float((uint32_t)(e + 127) << 23);
  return fmaxf(y * s, xin);
}

// -------- XLA CPU log (classic single-Horner Cephes, fused) --------
__device__ __forceinline__ float elog(float xin) {
  float x = fmaxf(xin, 1.17549435e-38f);
  uint32_t bits = __float_as_uint(x);
  float e = (float)((int)(bits >> 23) - 0x7e);
  x = __uint_as_float((bits & 0x807fffffu) | 0x3f000000u);
  bool mask = x < 0.707106781186547524f;
  float tmp = mask ? x : 0.0f;
  x = x - 1.0f;
  e = e - (mask ? 1.0f : 0.0f);
  x = x + tmp;
  float z = x * x;
  float y = __builtin_fmaf(7.0376836292e-2f, x, -1.1514610310e-1f);
  y = __builtin_fmaf(y, x, 1.1676998740e-1f);
  y = __builtin_fmaf(y, x, -1.2420140846e-1f);
  y = __builtin_fmaf(y, x, 1.4249322787e-1f);
  y = __builtin_fmaf(y, x, -1.6668057665e-1f);
  y = __builtin_fmaf(y, x, 2.0000714765e-1f);
  y = __builtin_fmaf(y, x, -2.4999993993e-1f);
  y = __builtin_fmaf(y, x, 3.3333331174e-1f);
  y = y * x;
  y = y * z;
  y = __builtin_fmaf(e, -2.12194440e-4f, y);
  y = __builtin_fmaf(-0.5f, z, y);
  x = x + y;
  x = __builtin_fmaf(e, 0.693359375f, x);
  if (xin == 0.0f) x = -__builtin_inff();
  return x;
}

__device__ __forceinline__ float xlog1p(float x) {
  float small_ = __builtin_fmaf(-0.5f, x, 1.0f) * x;
  float large_ = elog(x + 1.0f);
  return (fabsf(x) < 1e-4f) ? small_ : large_;
}

__device__ __forceinline__ float xlgamma(float input) {
  float z = input - 1.0f;
  float x = 0.99999999999980993227684700473478f;
  const float lcs[8] = {
      676.520368121885098567009190444019f,
      -1259.13921672240287047156078755283f,
      771.3234287776530788486528258894f,
      -176.61502916214059906584551354f,
      12.507343278686904814458936853f,
      -0.13857109526572011689554707f,
      9.984369578019570859563e-6f,
      1.50563273514931155834e-7f};
#pragma unroll
  for (int i = 0; i < 8; ++i) {
    x = x + lcs[i] / ((z + (float)i) + 1.0f);
  }
  float t = 7.5f + z;
  float log_t = 2.0149030205422647f + xlog1p(z / 7.5f);
  float log_y = __builtin_fmaf((z + 0.5f) - t / log_t, log_t,
                               0.91893853320467274178f) + elog(x);
  return log_y;
}

struct TrsP { float ll, bb, aa, ia, vr; };
__device__ __forceinline__ TrsP trs_params(float lam) {
  TrsP p;
  p.ll = elog(lam);
  p.bb = __builtin_fmaf(2.53f, csqrt(lam), 0.931f);
  p.aa = __builtin_fmaf(0.02483f, p.bb, -0.059f);
  p.ia = 1.1239f + 1.1328f / (p.bb - 3.4f);
  p.vr = 0.9277f - 3.6224f / (p.bb - 2.0f);
  return p;
}

__device__ __forceinline__ bool trs_step(float lam, const TrsP& p,
                                         float u, float v, float& kout) {
  float us = 0.5f - fabsf(u);
  float t2 = (2.0f * p.aa) / us + p.bb;
  float k = floorf(__builtin_fmaf(t2, u, lam) + 0.43f);
  kout = k;
  bool accept1 = (us >= 0.07f) && (v <= p.vr);
  if (accept1) return true;
  bool reject = (k < 0.0f) || ((us < 0.013f) && (v > us));
  if (reject) return false;
  float s = elog(v * p.ia / (p.aa / (us * us) + p.bb));
  float tt = __builtin_fmaf(k, p.ll, -lam) - xlgamma(k + 1.0f);
  return s <= tt;
}

// ---------------- chain + consts ----------------
__global__ void chain_v2(uint32_t* __restrict__ ws) {
  int lane = threadIdx.x;
  uint32_t kpa = 0, kpb = 0;
  if (lane == 0) {
    uint32_t a0, b0;
    tf2x32(0u, 42u, 0u, 0u, kpa, kpb);
    tf2x32(0u, 42u, 0u, 1u, a0, b0);
    ws[0] = a0; ws[1] = b0;
  }
  kpa = __shfl(kpa, 0); kpb = __shfl(kpb, 0);
  uint32_t kra = kpa, krb = kpb;
  uint32_t kja = kpa, kjb = kpb;
  for (int i = 0; i < 64; ++i) {
    bool isrej = (lane >= 2 && lane <= 4);
    uint32_t key0 = isrej ? kja : kra;
    uint32_t key1 = isrej ? kjb : krb;
    uint32_t xx = (lane == 1) ? 1u : (lane == 3) ? 1u : (lane == 4) ? 2u : 0u;
    uint32_t o0, o1;
    tf2x32(key0, key1, 0u, xx, o0, o1);
    if (lane == 1) { ws[2 + 2 * i] = o0; ws[3 + 2 * i] = o1; }
    if (lane == 3) { ws[130 + 4 * i] = o0; ws[131 + 4 * i] = o1; }
    if (lane == 4) { ws[132 + 4 * i] = o0; ws[133 + 4 * i] = o1; }
    kra = __shfl(o0, 0); krb = __shfl(o1, 0);
    kja = __shfl(o0, 2); kjb = __shfl(o1, 2);
  }
  if (lane == 0) {
    TrsP p = trs_params(1e5f);
    float* wf = (float*)(ws + WS_P1E5);
    wf[0] = p.ll; wf[1] = p.bb; wf[2] = p.aa; wf[3] = p.ia; wf[4] = p.vr;
    ws[WS_TSLOT] = 0u;
    ws[WS_RCNT] = 0u;
  }
}

__global__ __launch_bounds__(256) void lgt_kernel(uint32_t* __restrict__ ws) {
  int j = blockIdx.x * 256 + threadIdx.x;
  if (j >= TBL_N) return;
  float* tbl = (float*)((char*)ws + TBL_OFF_B);
  tbl[j] = xlgamma((float)(TBL_K0 + j) + 1.0f);
}

__global__ __launch_bounds__(256) void transpose_kernel(
    const float* __restrict__ b, const float* __restrict__ g,
    float* __restrict__ bT, float* __restrict__ gT) {
  int i = blockIdx.x * 256 + threadIdx.x;
  int q = i >> 7, d = i & 127;
  bT[d * 512 + q] = b[i];
  gT[d * 512 + q] = g[i];
}

// tiled transpose: [d>>2][q][d&3]
__global__ __launch_bounds__(256) void transpose_tiled(
    const float* __restrict__ b, const float* __restrict__ g,
    float* __restrict__ bTT, float* __restrict__ gTT) {
  int i = blockIdx.x * 256 + threadIdx.x;
  int q = i >> 7, d = i & 127;
  int dst = (d >> 2) * 2048 + (q << 2) + (d & 3);
  bTT[dst] = b[i];
  gTT[dst] = g[i];
}

// ---------------- pass1 eval (const lam = 1e5) ----------------
struct P1C { float ll, bb, aa, ia, vr; };

__device__ __forceinline__ bool p1_eval(const P1C& c, const float* __restrict__ tbl,
                                        uint32_t s00, uint32_t s01,
                                        uint32_t s10, uint32_t s11, uint32_t idx) {
  float u = u01(tfx(s00, s01, idx)) - 0.5f;
  float v = u01(tfx(s10, s11, idx));
  float us = 0.5f - fabsf(u);
  if (us >= 0.07f && v <= c.vr) return true;
  float t2 = (2.0f * c.aa) / us + c.bb;
  float k = floorf(__builtin_fmaf(t2, u, 1e5f) + 0.43f);
  if ((k < 0.0f) || ((us < 0.013f) && (v > us))) return false;
  float arg = v * c.ia / (c.aa / (us * us) + c.bb);
  int ki = (int)k - TBL_K0;
  float lg = (ki >= 0 && ki < TBL_N) ? tbl[ki] : xlgamma(k + 1.0f);
  float tt = __builtin_fmaf(k, c.ll, -1e5f) - lg;
  float sf = __logf(arg);
  if (sf <= tt - 1e-4f) return true;
  if (sf > tt + 1e-4f) return false;
  return elog(arg) <= tt;
}

__device__ uint32_t p1_scan(const P1C& c, const float* __restrict__ tbl,
                            const uint32_t* __restrict__ rej, uint32_t idx) {
  for (int it = 1; it < 64; ++it) {
    if (p1_eval(c, tbl, rej[4 * it], rej[4 * it + 1], rej[4 * it + 2],
                rej[4 * it + 3], idx))
      return (uint32_t)it;
  }
  return 63u;
}

// p1a v4: iter-0 eval; survivors -> per-block region (LDS counter, no global atomic)
__global__ __launch_bounds__(256) void p1a_v4(
    uint32_t* ws, uint32_t* __restrict__ p1wl, uint32_t* __restrict__ pcnt) {
  __shared__ uint32_t ldsc;
  if (threadIdx.x == 0) ldsc = 0;
  __syncthreads();
  const float* wf = (const float*)(ws + WS_P1E5);
  P1C c{wf[0], wf[1], wf[2], wf[3], wf[4]};
  const float* tbl = (const float*)((const char*)ws + TBL_OFF_B);
  const uint32_t* rej = ws + 130;
  uint32_t s00 = rej[0], s01 = rej[1], s10 = rej[2], s11 = rej[3];
  uint32_t t = blockIdx.x * 256u + threadIdx.x;
  uint32_t* region = p1wl + blockIdx.x * PCAP_BLK;
  bool fa = !p1_eval(c, tbl, s00, s01, s10, s11, t);
  bool fb = !p1_eval(c, tbl, s00, s01, s10, s11, t + HALF_);
  if (fa) {
    uint32_t slot = atomicAdd(&ldsc, 1u);
    if (slot < PCAP_BLK) region[slot] = t;
    else atomicMax(ws + WS_TSLOT, p1_scan(c, tbl, rej, t));
  }
  if (fb) {
    uint32_t slot = atomicAdd(&ldsc, 1u);
    if (slot < PCAP_BLK) region[slot] = t + HALF_;
    else atomicMax(ws + WS_TSLOT, p1_scan(c, tbl, rej, t + HALF_));
  }
  __syncthreads();
  if (threadIdx.x == 0) pcnt[blockIdx.x] = ldsc;
}

// p1b v4: grid-stride over all slots; max-reduce into Tslot
__global__ __launch_bounds__(256) void p1b_v4(
    uint32_t* ws, const uint32_t* __restrict__ p1wl,
    const uint32_t* __restrict__ pcnt) {
  const float* wf = (const float*)(ws + WS_P1E5);
  P1C c{wf[0], wf[1], wf[2], wf[3], wf[4]};
  const float* tbl = (const float*)((const char*)ws + TBL_OFF_B);
  const uint32_t* rej = ws + 130;
  uint32_t fmax = 0;
  uint32_t total = NBLK * PCAP_BLK;
  for (uint32_t s = blockIdx.x * 256u + threadIdx.x; s < total;
       s += gridDim.x * 256u) {
    uint32_t b = s >> 7, i = s & (PCAP_BLK - 1u);
    uint32_t cnt = pcnt[b];
    if (cnt > PCAP_BLK) cnt = PCAP_BLK;
    if (i < cnt) {
      uint32_t f = p1_scan(c, tbl, rej, p1wl[s]);
      if (f > fmax) fmax = f;
    }
  }
  for (int off = 32; off > 0; off >>= 1) {
    uint32_t o = __shfl_down(fmax, off, 64);
    if (o > fmax) fmax = o;
  }
  if ((threadIdx.x & 63) == 0 && fmax > 0) atomicMax(ws + WS_TSLOT, fmax);
}

// exact first-accept with true lam (rejection elements only)
__device__ __forceinline__ int first_accept_exact(float lam, uint32_t idx,
                                                  const uint32_t* __restrict__ rej) {
  TrsP p = trs_params(lam);
  for (int it = 0; it < 64; ++it) {
    float u = u01(tfx(rej[4 * it + 0], rej[4 * it + 1], idx)) - 0.5f;
    float v = u01(tfx(rej[4 * it + 2], rej[4 * it + 3], idx));
    float kk;
    if (trs_step(lam, p, u, v, kk)) return it;
  }
  return 63;
}

// knuth finisher from state after 4 draws (k == 4), iters 4..63
__device__ float knuth_finish(float lp, float lam, bool fD, bool m,
                              const uint32_t* __restrict__ wsk, uint32_t idx) {
  const float del = 4e-6f * (lam + 4.0f);
  int k = 4;
  bool fU = false;
  for (int it = 4; it < 64; ++it) {
    float d = lp + lam;
    bool nb = fabsf(d) < del;
    if (d > 0.0f) {
      fD = nb; k++;
      lp = lp + __logf(u01(tfx(wsk[2 * it], wsk[2 * it + 1], idx)));
    } else { fU = nb; break; }
  }
  float p = (float)(k - 1);
  float ph = p + ((fD && fU) ? 0.0f : (fD ? -0.5f : (fU ? 0.5f : 0.0f)));
  return m ? ph : 0.0f;
}

// ---------------- zip v4 ----------------
__global__ __launch_bounds__(256) void zip_v4(
    const float* __restrict__ z, uint32_t* ws,
    uint32_t* __restrict__ kwl, uint32_t* __restrict__ kcnt,
    float* __restrict__ out) {
  __shared__ uint32_t ldsc;
  if (threadIdx.x == 0) ldsc = 0;
  __syncthreads();
  uint32_t t = blockIdx.x * 256u + threadIdx.x;
  uint32_t n = t >> 9, q = t & 511u, n2 = n + 32768u;

  const float4* z4a = (const float4*)(z + (size_t)n * 128u);
  const float4* z4b = (const float4*)(z + (size_t)n2 * 128u);
  const float4* bt4 = (const float4*)((const char*)ws + BTT_OFF_B);
  const float4* gt4 = (const float4*)((const char*)ws + GTT_OFF_B);

  // UNFUSED sequential dot chains, ascending d (bit-exact)
  float lA = 0.f, lB = 0.f, gA = 0.f, gB = 0.f;
  for (int d4 = 0; d4 < 32; ++d4) {
    float4 bv = bt4[(d4 << 9) + q];
    float4 gv = gt4[(d4 << 9) + q];
    float4 z1 = z4a[d4], z2 = z4b[d4];
    lA = lA + z1.x * bv.x; lB = lB + z2.x * bv.x; gA = gA + z1.x * gv.x; gB = gB + z2.x * gv.x;
    lA = lA + z1.y * bv.y; lB = lB + z2.y * bv.y; gA = gA + z1.y * gv.y; gB = gB + z2.y * gv.y;
    lA = lA + z1.z * bv.z; lB = lB + z2.z * bv.z; gA = gA + z1.z * gv.z; gB = gB + z2.z * gv.z;
    lA = lA + z1.w * bv.w; lB = lB + z2.w * bv.w; gA = gA + z1.w * gv.w; gB = gB + z2.w * gv.w;
  }

  float piA = 1.0f / (1.0f + eexp(-lA));
  float piB = 1.0f / (1.0f + eexp(-lB));
  float lamA = fabsf(eexp(gA)) + 0.01f;
  float lamB = fabsf(eexp(gB)) + 0.01f;

  float dmA = u01(tfx(ws[0], ws[1], t)) - (1.0f - piA);
  float dmB = u01(tfx(ws[0], ws[1], t + HALF_)) - (1.0f - piB);
  bool mA = dmA < 0.0f, mB = dmB < 0.0f;
  bool mfA = fabsf(dmA) < 2e-6f, mfB = fabsf(dmB) < 2e-6f;

  bool knuA = lamA < 10.0f, knuB = lamB < 10.0f;

  // knuth chunk: exactly iterations 0..3
  const uint32_t* wsk = ws + 2;
  const float delA = 4e-6f * (lamA + 4.0f);
  const float delB = 4e-6f * (lamB + 4.0f);
  float lpA = 0.f, lpB = 0.f;
  int kA = 0, kB = 0;
  bool goA = knuA, goB = knuB;
  bool fDA = false, fUA = false, fDB = false, fUB = false;
#pragma unroll
  for (int it = 0; it < 4; ++it) {
    uint32_t w0 = wsk[2 * it], w1 = wsk[2 * it + 1];
    if (goA) {
      float d = lpA + lamA;
      bool nb = fabsf(d) < delA;
      if (d > 0.0f) { fDA = nb; kA++; lpA = lpA + __logf(u01(tfx(w0, w1, t))); }
      else          { fUA = nb; goA = false; }
    }
    if (goB) {
      float d = lpB + lamB;
      bool nb = fabsf(d) < delB;
      if (d > 0.0f) { fDB = nb; kB++; lpB = lpB + __logf(u01(tfx(w0, w1, t + HALF_))); }
      else          { fUB = nb; goB = false; }
    }
  }
  bool survA = knuA && goA, survB = knuB && goB;

  // rejection elements: exact first-accept -> T; push to rej WL (rare, ~1600)
  const uint32_t* rejk = ws + 130;
  uint32_t* rwl = (uint32_t*)((char*)ws + RWL_OFF_B);
  if (!knuA) {
    atomicMax(ws + WS_TSLOT, (uint32_t)first_accept_exact(lamA, t, rejk));
    uint32_t slot = atomicAdd(ws + WS_RCNT, 1u);
    if (slot < RWLCAP) {
      rwl[2 * slot] = t | (mA ? 0x80000000u : 0u);
      rwl[2 * slot + 1] = __float_as_uint(lamA);
    }
  }
  if (!knuB) {
    atomicMax(ws + WS_TSLOT, (uint32_t)first_accept_exact(lamB, t + HALF_, rejk));
    uint32_t slot = atomicAdd(ws + WS_RCNT, 1u);
    if (slot < RWLCAP) {
      rwl[2 * slot] = (t + HALF_) | (mB ? 0x80000000u : 0u);
      rwl[2 * slot + 1] = __float_as_uint(lamB);
    }
  }

  // knuth survivors -> per-block region (LDS counter); k3b recomputes lam/lp
  uint32_t* region = kwl + blockIdx.x * KCAP_BLK;
  if (survA) {
    uint32_t slot = atomicAdd(&ldsc, 1u);
    if (slot < KCAP_BLK) region[slot] = t | ((uint32_t)mA << 25);
    else out[t] = knuth_finish(lpA, lamA, fDA, mA, wsk, t);
  } else if (knuA) {
    float pA = (float)(kA - 1);
    float hiA = pA + (fUA ? 0.5f : 0.0f);
    float resA;
    if (mfA && hiA <= 1.2f) resA = 0.5f * hiA;
    else {
      float ph = pA + ((fDA && fUA) ? 0.0f : (fDA ? -0.5f : (fUA ? 0.5f : 0.0f)));
      resA = mA ? ph : 0.0f;
    }
    out[t] = resA;
  } else {
    out[t] = 0.0f;  // k3 overwrites
  }

  if (survB) {
    uint32_t slot = atomicAdd(&ldsc, 1u);
    if (slot < KCAP_BLK) region[slot] = (t + HALF_) | ((uint32_t)mB << 25);
    else out[t + HALF_] = knuth_finish(lpB, lamB, fDB, mB, wsk, t + HALF_);
  } else if (knuB) {
    float pB = (float)(kB - 1);
    float hiB = pB + (fUB ? 0.5f : 0.0f);
    float resB;
    if (mfB && hiB <= 1.2f) resB = 0.5f * hiB;
    else {
      float ph = pB + ((fDB && fUB) ? 0.0f : (fDB ? -0.5f : (fUB ? 0.5f : 0.0f)));
      resB = mB ? ph : 0.0f;
    }
    out[t + HALF_] = resB;
  } else {
    out[t + HALF_] = 0.0f;
  }
  __syncthreads();
  if (threadIdx.x == 0) kcnt[blockIdx.x] = ldsc;
}

// k3b v4: finish knuth survivors; recompute lam (bit-exact gamma-dot) and lp
__global__ __launch_bounds__(256) void k3b_v4(
    uint32_t* ws, const float* __restrict__ z,
    const uint32_t* __restrict__ kwl, const uint32_t* __restrict__ kcnt,
    float* __restrict__ out) {
  const uint32_t* wsk = ws + 2;
  const float4* gt4 = (const float4*)((const char*)ws + GTT_OFF_B);
  uint32_t total = NBLK * KCAP_BLK;
  for (uint32_t s = blockIdx.x * 256u + threadIdx.x; s < total;
       s += gridDim.x * 256u) {
    uint32_t b = s >> 7, i = s & (KCAP_BLK - 1u);
    uint32_t cnt = kcnt[b];
    if (cnt > KCAP_BLK) cnt = KCAP_BLK;
    if (i >= cnt) continue;
    uint32_t w = kwl[s];
    uint32_t idx = w & 0x01FFFFFFu;
    bool m = (w >> 25) & 1u;
    uint32_t n = idx >> 9, q = idx & 511u;
    const float4* z4 = (const float4*)(z + (size_t)n * 128u);
    // UNFUSED gamma-dot, same order as zip (bit-exact)
    float g = 0.f;
    for (int d4 = 0; d4 < 32; ++d4) {
      float4 gv = gt4[(d4 << 9) + q];
      float4 z1 = z4[d4];
      g = g + z1.x * gv.x;
      g = g + z1.y * gv.y;
      g = g + z1.z * gv.z;
      g = g + z1.w * gv.w;
    }
    float lam = fabsf(eexp(g)) + 0.01f;
    // replay iterations 0..3 (d>0 guaranteed for survivors)
    const float del = 4e-6f * (lam + 4.0f);
    float lp = 0.f;
    bool fD = false;
#pragma unroll
    for (int it = 0; it < 4; ++it) {
      float d = lp + lam;
      fD = fabsf(d) < del;
      lp = lp + __logf(u01(tfx(wsk[2 * it], wsk[2 * it + 1], idx)));
    }
    out[idx] = knuth_finish(lp, lam, fD, m, wsk, idx);
  }
}

// k3: rejection last-accept with final T
__global__ __launch_bounds__(256) void k3_kernel(
    const uint32_t* ws, const uint32_t* __restrict__ wl, uint32_t cap,
    float* __restrict__ out) {
  uint32_t cnt = ws[WS_RCNT];
  if (cnt > cap) cnt = cap;
  uint32_t Traw = ws[WS_TSLOT];
  int Tmax = (int)(Traw > 63u ? 63u : Traw);
  const uint32_t* rej = ws + 130;
  for (uint32_t i = blockIdx.x * 256u + threadIdx.x; i < cnt;
       i += gridDim.x * 256u) {
    uint32_t im = wl[2 * i];
    float lam = __uint_as_float(wl[2 * i + 1]);
    uint32_t idx = im & 0x7FFFFFFFu;
    bool mask = (im >> 31) != 0u;
    TrsP p = trs_params(lam);
    float klast = -1.0f;
    for (int it = 0; it <= Tmax; ++it) {
      float u = u01(tfx(rej[4 * it + 0], rej[4 * it + 1], idx)) - 0.5f;
      float v = u01(tfx(rej[4 * it + 2], rej[4 * it + 3], idx));
      float kk;
      if (trs_step(lam, p, u, v, kk)) klast = kk;
    }
    out[idx] = mask ? klast : 0.0f;
  }
}

// ================= v2 fallback (r11-verified) =================

__global__ __launch_bounds__(256) void pass1_lite(
    const uint32_t* __restrict__ chain, uint32_t* __restrict__ Tslot) {
  const float* wf = (const float*)(chain + WS_P1E5);
  P1C c{wf[0], wf[1], wf[2], wf[3], wf[4]};
  const float* tbl = (const float*)((const char*)chain + TBL_OFF_B);
  uint32_t t = blockIdx.x * 256u + threadIdx.x;
  const uint32_t* rej = chain + 130;
  int faA = 63, faB = 63;
  bool accA = false, accB = false;
  for (int it = 0; it < 64; ++it) {
    if (accA && accB) break;
    uint32_t s00 = rej[4 * it + 0], s01 = rej[4 * it + 1];
    uint32_t s10 = rej[4 * it + 2], s11 = rej[4 * it + 3];
    if (!accA && p1_eval(c, tbl, s00, s01, s10, s11, t)) { accA = true; faA = it; }
    if (!accB && p1_eval(c, tbl, s00, s01, s10, s11, t + HALF_)) { accB = true; faB = it; }
  }
  int fa = faA > faB ? faA : faB;
  for (int off = 32; off > 0; off >>= 1) {
    int o = __shfl_down(fa, off, 64);
    fa = fa > o ? fa : o;
  }
  __shared__ int smax[4];
  int wave = threadIdx.x >> 6, lanei = threadIdx.x & 63;
  if (lanei == 0) smax[wave] = fa;
  __syncthreads();
  if (threadIdx.x == 0) {
    int m01 = smax[0] > smax[1] ? smax[0] : smax[1];
    int m23 = smax[2] > smax[3] ? smax[2] : smax[3];
    int m = m01 > m23 ? m01 : m23;
    atomicMax(Tslot, (uint32_t)m);
  }
}

__global__ __launch_bounds__(256) void zip_v2(
    const float* __restrict__ z, const float* __restrict__ bT,
    const float* __restrict__ gT, uint32_t* ws, float* __restrict__ out) {
  uint32_t t = blockIdx.x * 256u + threadIdx.x;
  uint32_t n = t >> 9, q = t & 511u, n2 = n + 32768u;
  const float* zr  = z + (size_t)n * 128u;
  const float* zr2 = z + (size_t)n2 * 128u;
  float lA = 0.f, lB = 0.f, gA = 0.f, gB = 0.f;
  for (int d = 0; d < 128; ++d) {
    float bv = bT[d * 512 + q];
    float gv = gT[d * 512 + q];
    float z1 = zr[d], z2 = zr2[d];
    lA = lA + z1 * bv;
    lB = lB + z2 * bv;
    gA = gA + z1 * gv;
    gB = gB + z2 * gv;
  }
  float piA = 1.0f / (1.0f + eexp(-lA));
  float piB = 1.0f / (1.0f + eexp(-lB));
  float lamA = fabsf(eexp(gA)) + 0.01f;
  float lamB = fabsf(eexp(gB)) + 0.01f;
  bool knuA = lamA < 10.0f, knuB = lamB < 10.0f;
  float pA = 0.f, pB = 0.f;
  bool fDA = false, fUA = false, fDB = false, fUB = false;
  {
    const uint32_t* wsk = ws + 2;
    const float delA = 4e-6f * (lamA + 4.0f);
    const float delB = 4e-6f * (lamB + 4.0f);
    float lpA = 0.f, lpB = 0.f;
    int kA = 0, kB = 0;
    bool goA = knuA, goB = knuB;
    for (int it = 0; it < 64; ++it) {
      if (!goA && !goB) break;
      uint32_t w0 = wsk[2 * it], w1 = wsk[2 * it + 1];
      if (goA) {
        float d = lpA + lamA;
        bool nb = fabsf(d) < delA;
        if (d > 0.0f) { fDA = nb; kA++; lpA = lpA + __logf(u01(tfx(w0, w1, t))); }
        else          { fUA = nb; goA = false; }
      }
      if (goB) {
        float d = lpB + lamB;
        bool nb = fabsf(d) < delB;
        if (d > 0.0f) { fDB = nb; kB++; lpB = lpB + __logf(u01(tfx(w0, w1, t + HALF_))); }
        else          { fUB = nb; goB = false; }
      }
    }
    if (knuA) pA = (float)(kA - 1);
    if (knuB) pB = (float)(kB - 1);
  }
  float dmA = u01(tfx(ws[0], ws[1], t)) - (1.0f - piA);
  float dmB = u01(tfx(ws[0], ws[1], t + HALF_)) - (1.0f - piB);
  bool mA = dmA < 0.0f, mB = dmB < 0.0f;
  bool mfA = fabsf(dmA) < 2e-6f, mfB = fabsf(dmB) < 2e-6f;
  uint32_t* wl = (uint32_t*)((char*)ws + V2WL_OFF_B);
  const uint32_t* rejk = ws + 130;
  float resA, resB;
  if (!knuA) {
    atomicMax(ws + WS_TSLOT, (uint32_t)first_accept_exact(lamA, t, rejk));
    uint32_t slot = atomicAdd(ws + WS_RCNT, 1u);
    if (slot < V2WLCAP) {
      wl[2 * slot] = t | (mA ? 0x80000000u : 0u);
      wl[2 * slot + 1] = __float_as_uint(lamA);
    }
    resA = 0.0f;
  } else {
    float hiA = pA + (fUA ? 0.5f : 0.0f);
    if (mfA && hiA <= 1.2f) resA = 0.5f * hiA;
    else {
      float ph = pA + ((fDA && fUA) ? 0.0f : (fDA ? -0.5f : (fUA ? 0.5f : 0.0f)));
      resA = mA ? ph : 0.0f;
    }
  }
  if (!knuB) {
    atomicMax(ws + WS_TSLOT, (uint32_t)first_accept_exact(lamB, t + HALF_, rejk));
    uint32_t slot = atomicAdd(ws + WS_RCNT, 1u);
    if (slot < V2WLCAP) {
      wl[2 * slot] = (t + HALF_) | (mB ? 0x80000000u : 0u);
      wl[2 * slot + 1] = __float_as_uint(lamB);
    }
    resB = 0.0f;
  } else {
    float hiB = pB + (fUB ? 0.5f : 0.0f);
    if (mfB && hiB <= 1.2f) resB = 0.5f * hiB;
    else {
      float ph = pB + ((fDB && fUB) ? 0.0f : (fDB ? -0.5f : (fUB ? 0.5f : 0.0f)));
      resB = mB ? ph : 0.0f;
    }
  }
  out[t] = resA;
  out[t + HALF_] = resB;
}

extern "C" void kernel_launch(void* const* d_in, const int* in_sizes, int n_in,
                              void* d_out, int out_size, void* d_ws, size_t ws_size,
                              hipStream_t stream) {
  const float* z     = (const float*)d_in[0];
  const float* beta  = (const float*)d_in[1];
  const float* gamma = (const float*)d_in[2];
  float* out = (float*)d_out;
  uint32_t* ws = (uint32_t*)d_ws;

  if (ws_size >= NEED_V4) {
    float* bTT = (float*)((char*)d_ws + BTT_OFF_B);
    float* gTT = (float*)((char*)d_ws + GTT_OFF_B);
    uint32_t* p1wl = (uint32_t*)((char*)d_ws + P1WL_OFF_B);
    uint32_t* kwl  = (uint32_t*)((char*)d_ws + KWL_OFF_B);
    uint32_t* pcnt = (uint32_t*)((char*)d_ws + PCNT_OFF_B);
    uint32_t* kcnt = (uint32_t*)((char*)d_ws + KCNT_OFF_B);
    uint32_t* rwl  = (uint32_t*)((char*)d_ws + RWL_OFF_B);

    chain_v2<<<1, 64, 0, stream>>>(ws);
    lgt_kernel<<<(TBL_N + 255) / 256, 256, 0, stream>>>(ws);
    transpose_tiled<<<256, 256, 0, stream>>>(beta, gamma, bTT, gTT);
    p1a_v4<<<NBLK, 256, 0, stream>>>(ws, p1wl, pcnt);
    p1b_v4<<<2048, 256, 0, stream>>>(ws, p1wl, pcnt);
    zip_v4<<<NBLK, 256, 0, stream>>>(z, ws, kwl, kcnt, out);
    k3b_v4<<<2048, 256, 0, stream>>>(ws, z, kwl, kcnt, out);
    k3_kernel<<<64, 256, 0, stream>>>(ws, rwl, RWLCAP, out);
  } else {
    float* bT = (float*)((char*)d_ws + V2BT_OFF_B);
    float* gT = bT + 512 * 128;
    uint32_t* rwl = (uint32_t*)((char*)d_ws + V2WL_OFF_B);
    chain_v2<<<1, 64, 0, stream>>>(ws);
    lgt_kernel<<<(TBL_N + 255) / 256, 256, 0, stream>>>(ws);
    transpose_kernel<<<256, 256, 0, stream>>>(beta, gamma, bT, gT);
    pass1_lite<<<HALF_ / 256u, 256, 0, stream>>>(ws, ws + WS_TSLOT);
    zip_v2<<<HALF_ / 256u, 256, 0, stream>>>(z, bT, gT, ws, out);
    k3_kernel<<<64, 256, 0, stream>>>(ws, rwl, V2WLCAP, out);
  }
}